// Round 7
// baseline (257.751 us; speedup 1.0000x reference)
//
#include <hip/hip_runtime.h>

#define NREL 3
#define BSH 9              // 512 nodes per dst bucket
#define BNODES 512
#define NBLK_A 256         // blocks in hist/place passes

typedef __attribute__((ext_vector_type(8))) short short8;
typedef __attribute__((ext_vector_type(4))) float floatx4;

static __device__ inline float bf2f(unsigned short u) {
    union { unsigned int i; float f; } v; v.i = ((unsigned int)u) << 16; return v.f;
}
static __device__ inline unsigned short f2bf(float f) {
    union { float f; unsigned int i; } v; v.f = f;
    unsigned int x = v.i;
    return (unsigned short)((x + 0x7FFF + ((x >> 16) & 1)) >> 16);  // RNE
}
static __device__ inline float asf(unsigned int u) {
    union { unsigned int i; float f; } v; v.i = u; return v.f;
}

// ---------------------------------------------------------------------------
// K1: per-combo tables. x1tab[65][32] (row 64 = zeros, for pads),
//     root1t[64][64] (= x1@root1 + b1)
// ---------------------------------------------------------------------------
__global__ void build_tables(const float* __restrict__ pre_w, const float* __restrict__ pre_b,
                             const float* __restrict__ root1, const float* __restrict__ b1,
                             float* __restrict__ x1tab, float* __restrict__ root1t) {
    int combo = blockIdx.x, j = threadIdx.x;
    __shared__ float x1s[32];
    int s = combo >> 3, c = combo & 7;
    if (j < 32) {
        float v = pre_w[s * 32 + j] + pre_w[(8 + c) * 32 + j] + pre_b[j];
        v = v > 0.f ? v : 0.f;
        x1s[j] = v;
        x1tab[combo * 32 + j] = v;
    }
    __syncthreads();
    float acc = b1[j];
#pragma unroll
    for (int k = 0; k < 32; ++k) acc = fmaf(x1s[k], root1[k * 64 + j], acc);
    root1t[combo * 64 + j] = acc;
}

// ---------------------------------------------------------------------------
// K2: pre-shuffle weights into MFMA B-fragment layout (bf16).
// ---------------------------------------------------------------------------
__global__ void prep_B(const float* __restrict__ w1, const float* __restrict__ root2,
                       const float* __restrict__ w2,
                       unsigned short* __restrict__ B1f, unsigned short* __restrict__ B2f) {
    int t = blockIdx.x * blockDim.x + threadIdx.x;
    if (t < 4 * 8 * 64 * 8) {
        int i = t & 7, l = (t >> 3) & 63, kt = (t >> 9) & 7, nt = t >> 12;
        int k = kt * 32 + ((l >> 4) * 8) + i;
        int col = nt * 16 + (l & 15);
        float v = (k < 64) ? root2[k * 64 + col] : w2[(k - 64) * 64 + col];
        B2f[t] = f2bf(v);
    }
    if (t < 4 * 3 * 64 * 8) {
        int i = t & 7, l = (t >> 3) & 63;
        int rest = t >> 9;
        int kt = rest % 3, nt = rest / 3;
        int k = kt * 32 + ((l >> 4) * 8) + i;
        int col = nt * 16 + (l & 15);
        B1f[t] = f2bf(w1[k * 64 + col]);
    }
}

// K3: combo[i] as u8
__global__ void combo_kernel(const int* __restrict__ node_x, unsigned char* __restrict__ combo, int N) {
    int i = blockIdx.x * blockDim.x + threadIdx.x;
    if (i < N) combo[i] = (unsigned char)(node_x[2 * i] * 8 + node_x[2 * i + 1]);
}

// ---------------------------------------------------------------------------
// K4 (pass A0): per-block dst-bucket histogram. hist[b*NBLK_A + blk]
// ---------------------------------------------------------------------------
__global__ void __launch_bounds__(256) hist_kernel(const int* __restrict__ ei,
                                                   int* __restrict__ hist, int E, int NB, int chunk) {
    __shared__ int lh[256];
    for (int t = threadIdx.x; t < NB; t += 256) lh[t] = 0;
    __syncthreads();
    int s = blockIdx.x * chunk, e1 = min(E, s + chunk);
    for (int e = s + threadIdx.x; e < e1; e += 256)
        atomicAdd(&lh[ei[E + e] >> BSH], 1);
    __syncthreads();
    for (int b = threadIdx.x; b < NB; b += 256) hist[b * NBLK_A + blockIdx.x] = lh[b];
}

// generic exclusive scan (3 kernels)
__global__ void scan1(const int* __restrict__ in, int* __restrict__ out,
                      int* __restrict__ bsums, int n) {
    __shared__ int s[1024];
    int i = blockIdx.x * 1024 + threadIdx.x;
    int d = (i < n) ? in[i] : 0;
    s[threadIdx.x] = d;
    __syncthreads();
    for (int off = 1; off < 1024; off <<= 1) {
        int v = (threadIdx.x >= off) ? s[threadIdx.x - off] : 0;
        __syncthreads();
        s[threadIdx.x] += v;
        __syncthreads();
    }
    if (i < n) out[i] = s[threadIdx.x] - d;
    if (threadIdx.x == 1023) bsums[blockIdx.x] = s[1023];
}
__global__ void scan2(int* __restrict__ bsums, int nb) {
    __shared__ int s[128];
    int v = (threadIdx.x < nb) ? bsums[threadIdx.x] : 0;
    s[threadIdx.x] = v;
    __syncthreads();
    for (int off = 1; off < 128; off <<= 1) {
        int u = (threadIdx.x >= off) ? s[threadIdx.x - off] : 0;
        __syncthreads();
        s[threadIdx.x] += u;
        __syncthreads();
    }
    if (threadIdx.x < nb) bsums[threadIdx.x] = s[threadIdx.x] - v;
}
__global__ void scan3(int* __restrict__ out, const int* __restrict__ bsums, int n) {
    int i = blockIdx.x * 1024 + threadIdx.x;
    if (i < n) out[i] += bsums[blockIdx.x];
}

// ---------------------------------------------------------------------------
// K5 (pass A1): place edges into dst-buckets. staged = dloc<<19 | rel<<17 | src
// ---------------------------------------------------------------------------
__global__ void __launch_bounds__(256) place_kernel(const int* __restrict__ ei, const int* __restrict__ et,
                                                    const int* __restrict__ off, unsigned* __restrict__ staged,
                                                    int E, int NB, int chunk) {
    __shared__ int lh[256];
    for (int t = threadIdx.x; t < NB; t += 256) lh[t] = 0;
    __syncthreads();
    int s = blockIdx.x * chunk, e1 = min(E, s + chunk);
    for (int e = s + threadIdx.x; e < e1; e += 256) {
        int d = ei[E + e];
        int b = d >> BSH;
        int lr = atomicAdd(&lh[b], 1);
        int pos = off[b * NBLK_A + blockIdx.x] + lr;
        staged[pos] = ((unsigned)(d & (BNODES - 1)) << 19) | ((unsigned)et[e] << 17) | (unsigned)ei[e];
    }
}

// ---------------------------------------------------------------------------
// K6 (pass B): per-bucket finalize into rel-sorted, per-(node,rel)
// even-padded CSR. Segments (node, rel0|rel1|rel2) are contiguous; segment
// padded length = (c+1)&~1, derivable from cnt3 -> no extra metadata.
//   edges2[e] = src*32 (dword offset of h1 row; pad -> N*32, a zero row)
//   edges1[e] = combo(src)            (pad -> 64, a zero x1tab row)
//   base1[i]  = start of node i's rel-0 segment
//   cnt3[i]   = packed per-rel true counts (10 bits each)
// Bucket capacity = raw + 3*BNODES.
// ---------------------------------------------------------------------------
__global__ void __launch_bounds__(256) finalize_kernel(
        const unsigned* __restrict__ staged, const int* __restrict__ off,
        const unsigned char* __restrict__ combo,
        unsigned char* __restrict__ edges1, unsigned* __restrict__ edges2,
        int* __restrict__ base1, unsigned* __restrict__ cnt3,
        int E, int N, int NB) {
    __shared__ int lrel[BNODES * 3];   // counts -> placement cursors
    __shared__ int lraw[BNODES * 3];   // raw counts (for pad parity)
    __shared__ int part[256];
    int blk = blockIdx.x;
    int d0 = blk * BNODES;
    int nn = min(BNODES, N - d0);
    int estart = off[blk * NBLK_A];
    int eend = (blk == NB - 1) ? E : off[(blk + 1) * NBLK_A];
    int ebase = estart + blk * (BNODES * 3);   // padded-capacity base
    for (int t = threadIdx.x; t < BNODES * 3; t += 256) lrel[t] = 0;
    __syncthreads();
    for (int e = estart + threadIdx.x; e < eend; e += 256) {
        unsigned p = staged[e];
        atomicAdd(&lrel[(p >> 19) * 3 + ((p >> 17) & 3)], 1);
    }
    __syncthreads();
    // padded exclusive scan: 6 (node,rel) entries per thread = 2 nodes
    int t = threadIdx.x;
    int i0 = t * 6;
    int c[6], p6[6], sum = 0;
#pragma unroll
    for (int q = 0; q < 6; ++q) {
        c[q] = lrel[i0 + q];
        p6[q] = (c[q] + 1) & ~1;
        sum += p6[q];
    }
    part[t] = sum;
    __syncthreads();
    for (int o = 1; o < 256; o <<= 1) {
        int u = (t >= o) ? part[t - o] : 0;
        __syncthreads();
        part[t] += u;
        __syncthreads();
    }
    int run = ebase + part[t] - sum;
    int n0 = 2 * t, n1 = 2 * t + 1;
    if (n0 < nn) {
        base1[d0 + n0] = run;
        cnt3[d0 + n0] = (unsigned)c[0] | ((unsigned)c[1] << 10) | ((unsigned)c[2] << 20);
    }
#pragma unroll
    for (int q = 0; q < 6; ++q) {
        lraw[i0 + q] = c[q];
        lrel[i0 + q] = run;
        if (q == 2 && n1 < nn) {
            base1[d0 + n1] = run + p6[2];
            cnt3[d0 + n1] = (unsigned)c[3] | ((unsigned)c[4] << 10) | ((unsigned)c[5] << 20);
        }
        run += p6[q];
    }
    __syncthreads();
    for (int e = estart + threadIdx.x; e < eend; e += 256) {
        unsigned p = staged[e];
        int j = (p >> 19) * 3 + ((p >> 17) & 3);
        unsigned src = p & 0x1FFFF;
        int slot = atomicAdd(&lrel[j], 1);
        edges2[slot] = src << 5;
        edges1[slot] = combo[src];
    }
    __syncthreads();
    for (int j = threadIdx.x; j < nn * 3; j += 256) {
        if (lraw[j] & 1) {                 // one dummy pad -> zero rows
            int slot = lrel[j];
            edges2[slot] = (unsigned)N << 5;
            edges1[slot] = 64;
        }
    }
}

// ---------------------------------------------------------------------------
// K7: conv1 aggregation. Wave per node; rel-sorted segments, no rel decode.
// ---------------------------------------------------------------------------
__global__ void __launch_bounds__(256) agg1_kernel(
        const unsigned char* __restrict__ edges1, const int* __restrict__ base1,
        const unsigned* __restrict__ cnt3, const float* __restrict__ x1tab,
        unsigned short* __restrict__ AGG1, int N) {
    __shared__ float tab[65 * 32];
    for (int t = threadIdx.x; t < 65 * 32; t += 256) tab[t] = x1tab[t];
    __syncthreads();
    int i = blockIdx.x * 4 + (threadIdx.x >> 6);
    if (i >= N) return;
    int lane = threadIdx.x & 63;
    int k = lane & 31, half = lane >> 5;
    int s = base1[i];
    unsigned c3 = cnt3[i];
#pragma unroll
    for (int r = 0; r < 3; ++r) {
        unsigned c = (c3 >> (10 * r)) & 1023;
        int L = (c + 1) & ~1;
        float a = 0.f;
        int t2 = 0;
        for (; t2 + 4 <= L; t2 += 4) {
            unsigned wA = edges1[s + t2 + half];
            unsigned wB = edges1[s + t2 + 2 + half];
            a += tab[wA * 32 + k] + tab[wB * 32 + k];
        }
        if (t2 < L) a += tab[(unsigned)edges1[s + t2 + half] * 32 + k];
        a += __shfl_xor(a, 32);
        if (half == 0)
            AGG1[(size_t)i * 96 + r * 32 + k] = f2bf(a * (c ? 1.f / (float)c : 0.f));
        s += L;
    }
}

// ---------------------------------------------------------------------------
// K8: conv1 transform. MFMA [16,96]@[96,64] + root-table epilogue -> h1 bf16
// ---------------------------------------------------------------------------
__global__ void __launch_bounds__(256) gemm1_kernel(
        const unsigned short* __restrict__ AGG1, const unsigned short* __restrict__ B1f,
        const float* __restrict__ root1t, const unsigned char* __restrict__ combo,
        unsigned short* __restrict__ h1, int N) {
    int g = blockIdx.x * 4 + (threadIdx.x >> 6);
    int node0 = g * 16;
    if (node0 >= N) return;
    int lane = threadIdx.x & 63;
    int m = lane & 15, kg = lane >> 4;
    short8 a[3];
#pragma unroll
    for (int kt = 0; kt < 3; ++kt)
        a[kt] = *(const short8*)(AGG1 + (size_t)(node0 + m) * 96 + kt * 32 + kg * 8);
#pragma unroll
    for (int nt = 0; nt < 4; ++nt) {
        floatx4 c = {0.f, 0.f, 0.f, 0.f};
#pragma unroll
        for (int kt = 0; kt < 3; ++kt) {
            short8 b = *(const short8*)(B1f + ((nt * 3 + kt) * 64 + lane) * 8);
            c = __builtin_amdgcn_mfma_f32_16x16x32_bf16(a[kt], b, c, 0, 0, 0);
        }
#pragma unroll
        for (int q = 0; q < 4; ++q) {
            int node = node0 + kg * 4 + q;
            if (node < N) {
                float v = c[q] + root1t[(int)combo[node] * 64 + nt * 16 + m];
                v = v > 0.f ? v : 0.f;
                h1[(size_t)node * 64 + nt * 16 + m] = f2bf(v);
            }
        }
    }
}

// ---------------------------------------------------------------------------
// K9: conv2 aggregation. Wave per node; rel-sorted segments, no rel decode.
// Half-wave h takes edges s+2t+h; each lane loads a dword (2 bf16 dims).
// Pads point at h1 row N (zeroed).
// ---------------------------------------------------------------------------
__global__ void __launch_bounds__(256) agg2_kernel(
        const unsigned* __restrict__ edges2, const int* __restrict__ base1,
        const unsigned* __restrict__ cnt3, const unsigned* __restrict__ h1u,
        unsigned* __restrict__ AGG2u, int N) {
    int i = blockIdx.x * 4 + (threadIdx.x >> 6);
    if (i >= N) return;
    int lane = threadIdx.x & 63;
    int l32 = lane & 31, half = lane >> 5;
    int s = base1[i];
    unsigned c3 = cnt3[i];
#pragma unroll
    for (int r = 0; r < 3; ++r) {
        unsigned c = (c3 >> (10 * r)) & 1023;
        int L = (c + 1) & ~1;
        float aLo = 0.f, aHi = 0.f;
        int t2 = 0;
        for (; t2 + 4 <= L; t2 += 4) {
            unsigned pA = edges2[s + t2 + half];
            unsigned pB = edges2[s + t2 + 2 + half];
            unsigned vA = h1u[pA + l32];
            unsigned vB = h1u[pB + l32];
            aLo += asf(vA << 16); aHi += asf(vA & 0xFFFF0000u);
            aLo += asf(vB << 16); aHi += asf(vB & 0xFFFF0000u);
        }
        if (t2 < L) {
            unsigned pA = edges2[s + t2 + half];
            unsigned vA = h1u[pA + l32];
            aLo += asf(vA << 16); aHi += asf(vA & 0xFFFF0000u);
        }
        aLo += __shfl_xor(aLo, 32);
        aHi += __shfl_xor(aHi, 32);
        if (half == 0) {
            float sc = c ? 1.f / (float)c : 0.f;
            AGG2u[(size_t)i * 96 + r * 32 + l32] =
                (unsigned)f2bf(aLo * sc) | ((unsigned)f2bf(aHi * sc) << 16);
        }
        s += L;
    }
}

// ---------------------------------------------------------------------------
// K10: conv2 transform. MFMA [16,256]@[256,64] -> h2 bf16 (relu deferred)
// ---------------------------------------------------------------------------
__global__ void __launch_bounds__(256) gemm2_kernel(
        const unsigned short* __restrict__ h1, const unsigned short* __restrict__ AGG2,
        const unsigned short* __restrict__ B2f, const float* __restrict__ b2,
        unsigned short* __restrict__ h2, int N) {
    int g = blockIdx.x * 4 + (threadIdx.x >> 6);
    int node0 = g * 16;
    if (node0 >= N) return;
    int lane = threadIdx.x & 63;
    int m = lane & 15, kg = lane >> 4;
    short8 a[8];
#pragma unroll
    for (int kt = 0; kt < 2; ++kt)
        a[kt] = *(const short8*)(h1 + (size_t)(node0 + m) * 64 + kt * 32 + kg * 8);
#pragma unroll
    for (int kt = 2; kt < 8; ++kt)
        a[kt] = *(const short8*)(AGG2 + (size_t)(node0 + m) * 192 + (kt - 2) * 32 + kg * 8);
#pragma unroll
    for (int nt = 0; nt < 4; ++nt) {
        floatx4 c = {0.f, 0.f, 0.f, 0.f};
#pragma unroll
        for (int kt = 0; kt < 8; ++kt) {
            short8 b = *(const short8*)(B2f + ((nt * 8 + kt) * 64 + lane) * 8);
            c = __builtin_amdgcn_mfma_f32_16x16x32_bf16(a[kt], b, c, 0, 0, 0);
        }
        float bias = b2[nt * 16 + m];
#pragma unroll
        for (int q = 0; q < 4; ++q) {
            int node = node0 + kg * 4 + q;
            if (node < N)
                h2[(size_t)node * 64 + nt * 16 + m] = f2bf(c[q] + bias);
        }
    }
}

// ---------------------------------------------------------------------------
// K11: mean-pool (sorted batch -> binary search) + classifier; relu folded.
// ---------------------------------------------------------------------------
__global__ void __launch_bounds__(64) pool_cls(
        const unsigned short* __restrict__ h2, const int* __restrict__ batch,
        const float* __restrict__ cls_w, const float* __restrict__ cls_b,
        float* __restrict__ out, int N, int G) {
    int g = blockIdx.x, lane = threadIdx.x;
    auto lb = [&](int key) {
        int lo = 0, hi = N;
        while (lo < hi) { int mid = (lo + hi) >> 1; if (batch[mid] < key) lo = mid + 1; else hi = mid; }
        return lo;
    };
    int start = lb(g), end = lb(g + 1);
    float sum = 0.f;
    for (int i = start; i < end; ++i) {
        float v = bf2f(h2[(size_t)i * 64 + lane]);
        sum += v > 0.f ? v : 0.f;
    }
    int cntn = end - start;
    float pooled = sum / (float)(cntn > 0 ? cntn : 1);
    __shared__ float ps[64];
    ps[lane] = pooled;
    __syncthreads();
    if (lane < 10) {
        float o = cls_b[lane];
#pragma unroll
        for (int j = 0; j < 64; ++j) o = fmaf(ps[j], cls_w[j * 10 + lane], o);
        out[g * 10 + lane] = o;
    }
}

// ---------------------------------------------------------------------------
extern "C" void kernel_launch(void* const* d_in, const int* in_sizes, int n_in,
                              void* d_out, int out_size, void* d_ws, size_t ws_size,
                              hipStream_t stream) {
    const int*   node_x = (const int*)d_in[0];
    const int*   ei     = (const int*)d_in[1];
    const int*   et     = (const int*)d_in[2];
    const int*   batch  = (const int*)d_in[3];
    const float* pre_w  = (const float*)d_in[4];
    const float* pre_b  = (const float*)d_in[5];
    const float* w1     = (const float*)d_in[6];
    const float* root1  = (const float*)d_in[7];
    const float* b1     = (const float*)d_in[8];
    const float* w2     = (const float*)d_in[9];
    const float* root2  = (const float*)d_in[10];
    const float* b2     = (const float*)d_in[11];
    const float* cls_w  = (const float*)d_in[12];
    const float* cls_b  = (const float*)d_in[13];
    float* out = (float*)d_out;

    int N = in_sizes[0] / 2;
    int E = in_sizes[1] / 2;
    int G = out_size / 10;

    int NB = (N + BNODES - 1) >> BSH;
    int chunk = (E + NBLK_A - 1) / NBLK_A;
    int nh = NB * NBLK_A;
    int nscan = (nh + 1023) / 1024;
    int EP = E + NB * BNODES * 3;      // padded edge capacity

    char* ws = (char*)d_ws;
    size_t off_b = 0;
    auto alloc = [&](size_t bytes) {
        void* p = ws + off_b;
        off_b = (off_b + bytes + 255) & ~(size_t)255;
        return p;
    };
    float*          x1tab  = (float*)alloc(65 * 32 * sizeof(float));
    float*          root1t = (float*)alloc(64 * 64 * sizeof(float));
    unsigned short* B1f    = (unsigned short*)alloc(4 * 3 * 64 * 8 * sizeof(short));
    unsigned short* B2f    = (unsigned short*)alloc(4 * 8 * 64 * 8 * sizeof(short));
    unsigned char*  combo  = (unsigned char*)alloc((size_t)N + 64);
    int*            hist   = (int*)alloc((size_t)nh * sizeof(int));
    int*            hoff   = (int*)alloc((size_t)nh * sizeof(int));
    int*            bsums  = (int*)alloc(128 * sizeof(int));
    unsigned*       staged = (unsigned*)alloc((size_t)E * sizeof(unsigned));
    unsigned char*  edges1 = (unsigned char*)alloc((size_t)EP);
    unsigned*       edges2 = (unsigned*)alloc((size_t)EP * sizeof(unsigned));
    int*            base1  = (int*)alloc(((size_t)N + 8) * sizeof(int));
    unsigned*       cnt3   = (unsigned*)alloc((size_t)N * sizeof(unsigned));
    unsigned short* h1     = (unsigned short*)alloc((size_t)(N + 16) * 64 * sizeof(short));
    unsigned short* h2     = (unsigned short*)alloc((size_t)(N + 16) * 64 * sizeof(short));
    unsigned short* AGGbuf = (unsigned short*)alloc((size_t)(N + 16) * 192 * sizeof(short));
    unsigned short* AGG1 = AGGbuf;             // [N+16][96]  (dead before AGG2 written)
    unsigned*       AGG2u = (unsigned*)AGGbuf; // [N+16][96] u32 = [N+16][192] bf16

    // zero rows used by pads: x1tab row 64, h1 rows N..N+15
    hipMemsetAsync(x1tab + 64 * 32, 0, 32 * sizeof(float), stream);
    hipMemsetAsync(h1 + (size_t)N * 64, 0, 16 * 64 * sizeof(short), stream);

    build_tables<<<64, 64, 0, stream>>>(pre_w, pre_b, root1, b1, x1tab, root1t);
    prep_B<<<64, 256, 0, stream>>>(w1, root2, w2, B1f, B2f);
    combo_kernel<<<(N + 255) / 256, 256, 0, stream>>>(node_x, combo, N);

    hist_kernel<<<NBLK_A, 256, 0, stream>>>(ei, hist, E, NB, chunk);
    scan1<<<nscan, 1024, 0, stream>>>(hist, hoff, bsums, nh);
    scan2<<<1, 128, 0, stream>>>(bsums, nscan);
    scan3<<<nscan, 1024, 0, stream>>>(hoff, bsums, nh);
    place_kernel<<<NBLK_A, 256, 0, stream>>>(ei, et, hoff, staged, E, NB, chunk);
    finalize_kernel<<<NB, 256, 0, stream>>>(staged, hoff, combo, edges1, edges2,
                                            base1, cnt3, E, N, NB);

    agg1_kernel<<<(N + 3) / 4, 256, 0, stream>>>(edges1, base1, cnt3, x1tab, AGG1, N);
    gemm1_kernel<<<((N + 15) / 16 + 3) / 4, 256, 0, stream>>>(AGG1, B1f, root1t, combo, h1, N);
    agg2_kernel<<<(N + 3) / 4, 256, 0, stream>>>(edges2, base1, cnt3,
                                                 (const unsigned*)h1, AGG2u, N);
    gemm2_kernel<<<((N + 15) / 16 + 3) / 4, 256, 0, stream>>>(h1, (const unsigned short*)AGG2u,
                                                              B2f, b2, h2, N);
    pool_cls<<<G, 64, 0, stream>>>(h2, batch, cls_w, cls_b, out, N, G);
}